// Round 6
// baseline (344.693 us; speedup 1.0000x reference)
//
#include <hip/hip_runtime.h>
#include <hip/hip_bf16.h>
#include <cstdint>

#define NF_   4
#define NLOC_ 4096
#define NALL_ 4096
#define NNEI_ 128
#define RCUT_ 6.0f
#define RMIN_ 0.5f

typedef __attribute__((ext_vector_type(8))) short    bhalf8;
typedef __attribute__((ext_vector_type(4))) float    f32x4;
typedef __attribute__((ext_vector_type(4))) unsigned u32x4;

// fast tanh via hardware exp + rcp: tanh(x) = 1 - 2/(exp(2x)+1); saturates correctly
__device__ __forceinline__ float fast_tanh(float x) {
    float e = __expf(2.0f * x);
    return 1.0f - 2.0f * __builtin_amdgcn_rcpf(e + 1.0f);
}
__device__ __forceinline__ unsigned short bfb(float v) {   // float -> bf16 bits (RNE)
    return __builtin_bit_cast(unsigned short, __float2bfloat16(v));
}
__device__ __forceinline__ float bff(unsigned short b) {
    return __builtin_bit_cast(float, (unsigned)b << 16);
}
__device__ __forceinline__ unsigned pk(float a, float b) { // pack 2 bf16
    return (unsigned)bfb(a) | ((unsigned)bfb(b) << 16);
}
__device__ __forceinline__ float bf16_lo(unsigned u) {
    return __builtin_bit_cast(float, u << 16);
}
__device__ __forceinline__ float bf16_hi(unsigned u) {
    return __builtin_bit_cast(float, u & 0xffff0000u);
}

// LDS map (uint words), total 7168 = 28672 B -> 5 blocks/CU:
//  [0,512)       envs  float[128][4]        (dead after envA build)
//  [512,2304)    h1L   uint[128][14]        (bf16x2; dead after layer2t epilogue)
//  [0,2112)      GsT   uint[32][66]         (OVERLAY envs+h1L; tanhY col-major per slab)
//  [2304,2688)   Th2L  float[2][4][48]
//  [2688,3456)   TyL   float[2][4][96]
//  [3456,3840)   Ts    float[4][96]
//  [3840,7168)   h2L   uint[128][26]        (bf16x2 row-major, 48 ch, no pad)
__global__ __launch_bounds__(128, 4)
void descrpt_sea_kernel(
    const float* __restrict__ coord,
    const float* __restrict__ davg,
    const float* __restrict__ dstd,
    const float* __restrict__ w1, const float* __restrict__ b1,
    const float* __restrict__ w2, const float* __restrict__ b2,
    const float* __restrict__ w3, const float* __restrict__ b3,
    const int*   __restrict__ nlist,
    float* __restrict__ out)
{
    __shared__ __align__(16) unsigned smem[7168];
    float*    envs = (float*)smem;
    unsigned* h1L  = smem + 512;
    unsigned* GsT  = smem;                  // overlay
    float*    Th2L = (float*)(smem + 2304);
    float*    TyL  = (float*)(smem + 2688);
    float*    Ts   = (float*)(smem + 3456);
    unsigned* h2L  = smem + 3840;

    const int t = threadIdx.x;              // 0..127: neighbor slot / pair row
    const int a = blockIdx.x;               // atom id (f*NLOC + i)
    const int f = a >> 12;
    const int i = a & 4095;

    // ---- phase 1: environment matrix row for this neighbor ----
    const float* cf = coord + (size_t)f * (NALL_ * 3);
    const float cix = cf[i * 3 + 0];
    const float ciy = cf[i * 3 + 1];
    const float ciz = cf[i * 3 + 2];
    const int nbr = nlist[(size_t)a * NNEI_ + t];
    float dx = cf[nbr * 3 + 0] - cix;
    float dy = cf[nbr * 3 + 1] - ciy;
    float dz = cf[nbr * 3 + 2] - ciz;
    float r2 = fmaf(dx, dx, fmaf(dy, dy, dz * dz)) + 1e-12f;
    float r  = __builtin_amdgcn_sqrtf(r2);
    float rinv = __builtin_amdgcn_rcpf(r);
    float uu = (r - RMIN_) * (1.0f / (RCUT_ - RMIN_));
    float u2 = uu * uu;
    float mid = (uu * u2) * fmaf(-6.0f, u2, fmaf(15.0f, uu, -10.0f)) + 1.0f;
    float sw  = (r < RMIN_) ? 1.0f : ((r < RCUT_) ? mid : 0.0f);
    float sv  = sw * rinv;
    float e0 = sv;
    float e1 = sv * dx * rinv;
    float e2 = sv * dy * rinv;
    float e3 = sv * dz * rinv;
    const float4 da  = reinterpret_cast<const float4*>(davg)[t];
    const float4 dsd = reinterpret_cast<const float4*>(dstd)[t];
    e0 = (e0 - da.x) * __builtin_amdgcn_rcpf(dsd.x);
    e1 = (e1 - da.y) * __builtin_amdgcn_rcpf(dsd.y);
    e2 = (e2 - da.z) * __builtin_amdgcn_rcpf(dsd.z);
    e3 = (e3 - da.w) * __builtin_amdgcn_rcpf(dsd.w);
    envs[t * 4 + 0] = e0;
    envs[t * 4 + 1] = e1;
    envs[t * 4 + 2] = e2;
    envs[t * 4 + 3] = e3;

    // ---- layer 1 per-lane (f32), h1 -> LDS bf16 row-major ----
    {
        const float x = e0;
        float h1[24];
#pragma unroll
        for (int j = 0; j < 24; ++j)
            h1[j] = fast_tanh(fmaf(x, w1[j], b1[j]));
#pragma unroll
        for (int j = 0; j < 12; ++j)
            h1L[t * 14 + j] = pk(h1[2 * j], h1[2 * j + 1]);
    }
    __syncthreads();   // B1: envs + h1L visible

    const int l   = t & 63;     // lane in wave
    const int w   = t >> 6;     // wave id (owns pair rows 64w..64w+63)
    const int m16 = l & 15;
    const int kg  = l >> 4;     // k-group 0..3

    // ---- layer 2 via MFMA, TRANSPOSED: Y2^T = w2^T . h1^T ----
    // C tile: col = pair (m16), rows = channels 16mt+4kg+reg -> epilogue writes
    // row-major h2L directly. K=24 padded to 32 with ZERO REGISTERS on kg==3.
    {
        // A-frags: A[m=channel][k=h1 idx] = w2[k][channel], kg==3 -> 0
        bhalf8 w2A[3];
#pragma unroll
        for (int mt = 0; mt < 3; ++mt) {
            bhalf8 av;
#pragma unroll
            for (int e = 0; e < 8; ++e) {
                const int kk = 8 * kg + e;
                av[e] = (kk < 24) ? (short)bfb(w2[kk * 48 + 16 * mt + m16])
                                  : (short)0;
            }
            w2A[mt] = av;
        }
        // acc init from b2 (bias per channel = C row)
        f32x4 acc2[3][4];
#pragma unroll
        for (int mt = 0; mt < 3; ++mt) {
            const float4 bi = *(const float4*)&b2[16 * mt + 4 * kg];
#pragma unroll
            for (int nt = 0; nt < 4; ++nt)
                acc2[mt][nt] = (f32x4){bi.x, bi.y, bi.z, bi.w};
        }
        // B-frags: B[k][n=pair] = h1[pair][k]; kg==3 -> 0
#pragma unroll
        for (int nt = 0; nt < 4; ++nt) {
            bhalf8 bv;
            if (kg < 3) {
                const int p = 64 * w + 16 * nt + m16;
                const uint2 u01 = *(const uint2*)&h1L[p * 14 + 4 * kg];
                const uint2 u23 = *(const uint2*)&h1L[p * 14 + 4 * kg + 2];
                bv = __builtin_bit_cast(bhalf8, (u32x4){u01.x, u01.y, u23.x, u23.y});
            } else {
#pragma unroll
                for (int e = 0; e < 8; ++e) bv[e] = 0;
            }
#pragma unroll
            for (int mt = 0; mt < 3; ++mt)
                acc2[mt][nt] = __builtin_amdgcn_mfma_f32_16x16x32_bf16(
                    w2A[mt], bv, acc2[mt][nt], 0, 0, 0);
        }
        // epilogue: h2 = tanh(y2) + h1[ch % 24]; write h2L row-major bf16x2
#pragma unroll
        for (int nt = 0; nt < 4; ++nt) {
            const int p = 64 * w + 16 * nt + m16;
#pragma unroll
            for (int mt = 0; mt < 3; ++mt) {
                const int cbase = 16 * mt + 4 * kg;          // 4 channels cbase..+3
                const int sbase = (cbase % 24) >> 1;         // even, no wrap
                const uint2 sk = *(const uint2*)&h1L[p * 14 + sbase];
                const float v0 = fast_tanh(acc2[mt][nt][0]) + bf16_lo(sk.x);
                const float v1 = fast_tanh(acc2[mt][nt][1]) + bf16_hi(sk.x);
                const float v2 = fast_tanh(acc2[mt][nt][2]) + bf16_lo(sk.y);
                const float v3 = fast_tanh(acc2[mt][nt][3]) + bf16_hi(sk.y);
                uint2 val;
                val.x = pk(v0, v1);
                val.y = pk(v2, v3);
                *(uint2*)&h2L[p * 26 + 8 * mt + 2 * kg] = val;
            }
        }
    }
    __syncthreads();   // B2a: h2L visible

    // ---- envA fragments: A[m][k], rows 0-3 = env_hi[d], rows 4-7 = env_lo[d] ----
    bhalf8 envA[2];
#pragma unroll
    for (int ks = 0; ks < 2; ++ks) {
        bhalf8 av;
#pragma unroll
        for (int e = 0; e < 8; ++e) {
            const int row = 64 * w + 32 * ks + 8 * kg + e;   // pair index (K dim)
            const float v = envs[row * 4 + (m16 & 3)];
            const unsigned short hb = bfb(v);
            const unsigned short lb = bfb(v - bff(hb));
            const unsigned short sel = (m16 < 4) ? hb : ((m16 < 8) ? lb : (unsigned short)0);
            av[e] = (short)sel;
        }
        envA[ks] = av;
    }

    // ---- h2A fragments for layer-3 A-operand: 4 Mtiles x 2 Kslices ----
    // K=48: ks=1 & kg>=2 -> zero registers (no LDS pad)
    bhalf8 h2A[4][2];
#pragma unroll
    for (int mt = 0; mt < 4; ++mt) {
        const int row = 64 * w + 16 * mt + m16;
        {
            const int wbase = row * 26 + 4 * kg;
            const uint2 u01 = *(const uint2*)&h2L[wbase];
            const uint2 u23 = *(const uint2*)&h2L[wbase + 2];
            h2A[mt][0] = __builtin_bit_cast(bhalf8, (u32x4){u01.x, u01.y, u23.x, u23.y});
        }
        if (kg < 2) {
            const int wbase = row * 26 + 16 + 4 * kg;
            const uint2 u01 = *(const uint2*)&h2L[wbase];
            const uint2 u23 = *(const uint2*)&h2L[wbase + 2];
            h2A[mt][1] = __builtin_bit_cast(bhalf8, (u32x4){u01.x, u01.y, u23.x, u23.y});
        } else {
            bhalf8 z;
#pragma unroll
            for (int e = 0; e < 8; ++e) z[e] = 0;
            h2A[mt][1] = z;
        }
    }

    // ---- Th2 = env^T h2 partial (resnet folded into T): 3 Ntiles of 16 ----
#pragma unroll
    for (int nt = 0; nt < 3; ++nt) {
        f32x4 acc = {0.f, 0.f, 0.f, 0.f};
#pragma unroll
        for (int ks = 0; ks < 2; ++ks) {
            bhalf8 bv;
#pragma unroll
            for (int e = 0; e < 8; ++e) {
                const int row = 64 * w + 32 * ks + 8 * kg + e;
                const int col = 16 * nt + m16;               // h2 channel
                const unsigned u = h2L[row * 26 + (col >> 1)];
                const unsigned short bits = (col & 1) ? (unsigned short)(u >> 16)
                                                      : (unsigned short)(u & 0xffffu);
                bv[e] = (short)bits;
            }
            acc = __builtin_amdgcn_mfma_f32_16x16x32_bf16(envA[ks], bv, acc, 0, 0, 0);
        }
#pragma unroll
        for (int rgi = 0; rgi < 4; ++rgi) {
            const float v = acc[rgi] + __shfl_down(acc[rgi], 16);  // hi + lo rows
            if (kg == 0) Th2L[(w * 4 + rgi) * 48 + 16 * nt + m16] = v;
        }
    }
    __syncthreads();   // B2b: envs/h1L reads done before GsT overlay writes

    // ---- layer 3 + Ty contraction, 3 N-slabs of 32 cols ----
#pragma unroll 1
    for (int sb = 0; sb < 3; ++sb) {
        const int nbase = 32 * sb;
        f32x4 acc[4][2];
#pragma unroll
        for (int nt = 0; nt < 2; ++nt) {
            const float b3v = b3[nbase + 16 * nt + m16];
#pragma unroll
            for (int mt = 0; mt < 4; ++mt)
                acc[mt][nt] = (f32x4){b3v, b3v, b3v, b3v};
        }
#pragma unroll
        for (int ks = 0; ks < 2; ++ks) {
#pragma unroll
            for (int nt = 0; nt < 2; ++nt) {
                bhalf8 wb;
#pragma unroll
                for (int e = 0; e < 8; ++e) {
                    const int k  = 32 * ks + 8 * kg + e;
                    const int kc = (k < 48) ? k : 47;
                    const float wv = w3[kc * 96 + nbase + 16 * nt + m16];
                    wb[e] = (short)((k < 48) ? bfb(wv) : (unsigned short)0);
                }
#pragma unroll
                for (int mt = 0; mt < 4; ++mt)
                    acc[mt][nt] = __builtin_amdgcn_mfma_f32_16x16x32_bf16(
                        h2A[mt][ks], wb, acc[mt][nt], 0, 0, 0);
            }
        }
        // epilogue: tanhY -> GsT col-major bf16 pairs
#pragma unroll
        for (int mt = 0; mt < 4; ++mt) {
#pragma unroll
            for (int nt = 0; nt < 2; ++nt) {
                const int col  = 16 * nt + m16;
                const int row0 = 64 * w + 16 * mt + 4 * kg;
                const float g0 = fast_tanh(acc[mt][nt][0]);
                const float g1 = fast_tanh(acc[mt][nt][1]);
                const float g2 = fast_tanh(acc[mt][nt][2]);
                const float g3 = fast_tanh(acc[mt][nt][3]);
                GsT[col * 66 + (row0 >> 1)]     = pk(g0, g1);
                GsT[col * 66 + (row0 >> 1) + 1] = pk(g2, g3);
            }
        }
        __syncthreads();   // B3: GsT writes ordered before reads
        // Ty partial for this slab's 32 cols
#pragma unroll
        for (int nt = 0; nt < 2; ++nt) {
            f32x4 ty = {0.f, 0.f, 0.f, 0.f};
#pragma unroll
            for (int ks = 0; ks < 2; ++ks) {
                const int col = 16 * nt + m16;
                const int wb2 = col * 66 + 32 * w + 16 * ks + 4 * kg;
                const uint2 u01 = *(const uint2*)&GsT[wb2];
                const uint2 u23 = *(const uint2*)&GsT[wb2 + 2];
                const bhalf8 bg = __builtin_bit_cast(bhalf8, (u32x4){u01.x, u01.y, u23.x, u23.y});
                ty = __builtin_amdgcn_mfma_f32_16x16x32_bf16(envA[ks], bg, ty, 0, 0, 0);
            }
#pragma unroll
            for (int rgi = 0; rgi < 4; ++rgi) {
                const float v = ty[rgi] + __shfl_down(ty[rgi], 16);
                if (kg == 0) TyL[(w * 4 + rgi) * 96 + nbase + 16 * nt + m16] = v;
            }
        }
        __syncthreads();   // B4: WAR before next slab's GsT overwrite / final combine
    }

    // ---- combine partials: Ts[d][n] = (Ty + tile(Th2)) / NNEI ----
#pragma unroll
    for (int j = 0; j < 3; ++j) {
        const int idx = t + 128 * j;         // 0..383
        const int d   = idx / 96;
        const int n   = idx - 96 * d;
        const int c   = (n >= 48) ? (n - 48) : n;
        const float v = TyL[(0 * 4 + d) * 96 + n] + TyL[(1 * 4 + d) * 96 + n]
                      + Th2L[(0 * 4 + d) * 48 + c] + Th2L[(1 * 4 + d) * 48 + c];
        Ts[d * 96 + n] = v * (1.0f / NNEI_);
    }
    __syncthreads();   // B5

    // ---- phase 4: D[m][k] = sum_d T[d][m]*T[d][k], k < 8 ----
    float* outp = out + (size_t)a * 768;
#pragma unroll
    for (int qq = 0; qq < 6; ++qq) {
        const int idx = t + 128 * qq;        // 0..767
        const int m = idx >> 3;
        const int k = idx & 7;
        const float d0 = Ts[0 * 96 + m] * Ts[0 * 96 + k];
        const float d1 = Ts[1 * 96 + m] * Ts[1 * 96 + k];
        const float d2 = Ts[2 * 96 + m] * Ts[2 * 96 + k];
        const float d3 = Ts[3 * 96 + m] * Ts[3 * 96 + k];
        outp[idx] = (d0 + d1) + (d2 + d3);
    }
}

extern "C" void kernel_launch(void* const* d_in, const int* in_sizes, int n_in,
                              void* d_out, int out_size, void* d_ws, size_t ws_size,
                              hipStream_t stream) {
    const float* coord = (const float*)d_in[0];
    const float* davg  = (const float*)d_in[1];
    const float* dstd  = (const float*)d_in[2];
    const float* w1    = (const float*)d_in[3];
    const float* b1    = (const float*)d_in[4];
    const float* w2    = (const float*)d_in[5];
    const float* b2    = (const float*)d_in[6];
    const float* w3    = (const float*)d_in[7];
    const float* b3    = (const float*)d_in[8];
    const int*   nlist = (const int*)d_in[9];
    float* outp = (float*)d_out;

    descrpt_sea_kernel<<<dim3(NF_ * NLOC_), dim3(128), 0, stream>>>(
        coord, davg, dstd, w1, b1, w2, b2, w3, b3, nlist, outp);
}

// Round 7
// 239.745 us; speedup vs baseline: 1.4377x; 1.4377x over previous
//
#include <hip/hip_runtime.h>
#include <hip/hip_bf16.h>
#include <cstdint>

#define NF_   4
#define NLOC_ 4096
#define NALL_ 4096
#define NNEI_ 128
#define RCUT_ 6.0f
#define RMIN_ 0.5f

typedef __attribute__((ext_vector_type(8))) short    bhalf8;
typedef __attribute__((ext_vector_type(4))) float    f32x4;
typedef __attribute__((ext_vector_type(4))) unsigned u32x4;

// fast tanh via hardware exp + rcp: tanh(x) = 1 - 2/(exp(2x)+1); saturates correctly
__device__ __forceinline__ float fast_tanh(float x) {
    float e = __expf(2.0f * x);
    return 1.0f - 2.0f * __builtin_amdgcn_rcpf(e + 1.0f);
}
__device__ __forceinline__ unsigned short bfb(float v) {   // float -> bf16 bits (RNE)
    return __builtin_bit_cast(unsigned short, __float2bfloat16(v));
}
__device__ __forceinline__ float bff(unsigned short b) {
    return __builtin_bit_cast(float, (unsigned)b << 16);
}
__device__ __forceinline__ unsigned pk(float a, float b) { // pack 2 bf16
    return (unsigned)bfb(a) | ((unsigned)bfb(b) << 16);
}
__device__ __forceinline__ float bf16_lo(unsigned u) {
    return __builtin_bit_cast(float, u << 16);
}
__device__ __forceinline__ float bf16_hi(unsigned u) {
    return __builtin_bit_cast(float, u & 0xffff0000u);
}

// ---------------- weight-fragment prepack (runs every launch, trivial cost) ----
// d_ws layout (uints):
//   [0,768)     w2A frags:  [mt 3][lane 64][4]   (bf16x2; K=24 padded to 32 w/ 0)
//   [768,3840)  w3  frags:  [sb 3][ks 2][nt 2][lane 64][4]  (K=48 padded w/ 0)
__global__ void prepack_weights(const float* __restrict__ w2,
                                const float* __restrict__ w3,
                                unsigned* __restrict__ ws) {
    const int idx = threadIdx.x + blockIdx.x * 256;
    if (idx < 768) {
        const int u   = idx & 3;
        const int l   = (idx >> 2) & 63;
        const int mt  = idx >> 8;            // 0..2
        const int m16 = l & 15, kg = l >> 4;
        const int k0  = 8 * kg + 2 * u;
        const unsigned short s0 = (k0 < 24)     ? bfb(w2[k0 * 48 + 16 * mt + m16])       : (unsigned short)0;
        const unsigned short s1 = (k0 + 1 < 24) ? bfb(w2[(k0 + 1) * 48 + 16 * mt + m16]) : (unsigned short)0;
        ws[idx] = (unsigned)s0 | ((unsigned)s1 << 16);
    } else if (idx < 3840) {
        const int j   = idx - 768;
        const int u   = j & 3;
        const int l   = (j >> 2) & 63;
        const int nt  = (j >> 8) & 1;
        const int ks  = (j >> 9) & 1;
        const int sb  = j >> 10;             // 0..2
        const int m16 = l & 15, kg = l >> 4;
        const int k0  = 32 * ks + 8 * kg + 2 * u;
        const int col = 32 * sb + 16 * nt + m16;
        const unsigned short s0 = (k0 < 48)     ? bfb(w3[k0 * 96 + col])       : (unsigned short)0;
        const unsigned short s1 = (k0 + 1 < 48) ? bfb(w3[(k0 + 1) * 96 + col]) : (unsigned short)0;
        ws[idx] = (unsigned)s0 | ((unsigned)s1 << 16);
    }
}

// LDS map (uint words), total 6016 = 24064 B -> 6 blocks/CU:
//  [0,512)       envs  float[128][4]       (dead after envA build)
//  [512,2304)    h1L   uint[128][14]       (bf16x2; dead after layer2t epilogue)
//  [0,2112)      GsT   uint[32][66]        (OVERLAY envs+h1L; tanhY col-major per slab)
//  [2304,2688)   Th2L  float[2][4][48]
//  [2688,6016)   h2L   uint[128][26]       (bf16x2 row-major; dead after Th2 / B2b)
//  [2688,3456)   TyL   float[2][4][96]     (OVERLAY h2L; written after B3 of sb=0)
//  [3456,3840)   Ts    float[4][96]        (OVERLAY h2L; written in final combine)
__global__ __launch_bounds__(128, 4)
void descrpt_sea_kernel(
    const float* __restrict__ coord,
    const float* __restrict__ davg,
    const float* __restrict__ dstd,
    const float* __restrict__ w1, const float* __restrict__ b1,
    const float* __restrict__ w2, const float* __restrict__ b2,
    const float* __restrict__ w3, const float* __restrict__ b3,
    const int*   __restrict__ nlist,
    const unsigned* __restrict__ wsp,
    float* __restrict__ out)
{
    __shared__ __align__(16) unsigned smem[6016];
    float*    envs = (float*)smem;
    unsigned* h1L  = smem + 512;
    unsigned* GsT  = smem;                  // overlay
    float*    Th2L = (float*)(smem + 2304);
    unsigned* h2L  = smem + 2688;
    float*    TyL  = (float*)(smem + 2688); // overlay (h2L dead by first write)
    float*    Ts   = (float*)(smem + 3456); // overlay

    const int t = threadIdx.x;              // 0..127: neighbor slot / pair row
    const int a = blockIdx.x;               // atom id (f*NLOC + i)
    const int f = a >> 12;
    const int i = a & 4095;

    // ---- phase 1: environment matrix row for this neighbor ----
    const float* cf = coord + (size_t)f * (NALL_ * 3);
    const float cix = cf[i * 3 + 0];
    const float ciy = cf[i * 3 + 1];
    const float ciz = cf[i * 3 + 2];
    const int nbr = nlist[(size_t)a * NNEI_ + t];
    float dx = cf[nbr * 3 + 0] - cix;
    float dy = cf[nbr * 3 + 1] - ciy;
    float dz = cf[nbr * 3 + 2] - ciz;
    float r2 = fmaf(dx, dx, fmaf(dy, dy, dz * dz)) + 1e-12f;
    float r  = __builtin_amdgcn_sqrtf(r2);
    float rinv = __builtin_amdgcn_rcpf(r);
    float uu = (r - RMIN_) * (1.0f / (RCUT_ - RMIN_));
    float u2 = uu * uu;
    float mid = (uu * u2) * fmaf(-6.0f, u2, fmaf(15.0f, uu, -10.0f)) + 1.0f;
    float sw  = (r < RMIN_) ? 1.0f : ((r < RCUT_) ? mid : 0.0f);
    float sv  = sw * rinv;
    float e0 = sv;
    float e1 = sv * dx * rinv;
    float e2 = sv * dy * rinv;
    float e3 = sv * dz * rinv;
    const float4 da  = reinterpret_cast<const float4*>(davg)[t];
    const float4 dsd = reinterpret_cast<const float4*>(dstd)[t];
    e0 = (e0 - da.x) * __builtin_amdgcn_rcpf(dsd.x);
    e1 = (e1 - da.y) * __builtin_amdgcn_rcpf(dsd.y);
    e2 = (e2 - da.z) * __builtin_amdgcn_rcpf(dsd.z);
    e3 = (e3 - da.w) * __builtin_amdgcn_rcpf(dsd.w);
    envs[t * 4 + 0] = e0;
    envs[t * 4 + 1] = e1;
    envs[t * 4 + 2] = e2;
    envs[t * 4 + 3] = e3;

    // ---- layer 1 per-lane (f32), h1 -> LDS bf16 row-major ----
    {
        const float x = e0;
        float h1[24];
#pragma unroll
        for (int j = 0; j < 24; ++j)
            h1[j] = fast_tanh(fmaf(x, w1[j], b1[j]));
#pragma unroll
        for (int j = 0; j < 12; ++j)
            h1L[t * 14 + j] = pk(h1[2 * j], h1[2 * j + 1]);
    }
    __syncthreads();   // B1: envs + h1L visible

    const int l   = t & 63;     // lane in wave
    const int w   = t >> 6;     // wave id (owns pair rows 64w..64w+63)
    const int m16 = l & 15;
    const int kg  = l >> 4;     // k-group 0..3

    // ---- layer 2 via MFMA, TRANSPOSED: Y2^T = w2^T . h1^T ----
    // C tile: col = pair (m16), rows = channels 16mt+4kg+reg -> epilogue writes
    // row-major h2L directly. A-frags prepacked in ws (K=24 padded to 32).
    {
        bhalf8 w2A[3];
#pragma unroll
        for (int mt = 0; mt < 3; ++mt)
            w2A[mt] = __builtin_bit_cast(bhalf8, *(const u32x4*)&wsp[(mt * 64 + l) * 4]);

        f32x4 acc2[3][4];
#pragma unroll
        for (int mt = 0; mt < 3; ++mt) {
            const float4 bi = *(const float4*)&b2[16 * mt + 4 * kg];
#pragma unroll
            for (int nt = 0; nt < 4; ++nt)
                acc2[mt][nt] = (f32x4){bi.x, bi.y, bi.z, bi.w};
        }
#pragma unroll
        for (int nt = 0; nt < 4; ++nt) {
            bhalf8 bv;
            if (kg < 3) {
                const int p = 64 * w + 16 * nt + m16;
                const uint2 u01 = *(const uint2*)&h1L[p * 14 + 4 * kg];
                const uint2 u23 = *(const uint2*)&h1L[p * 14 + 4 * kg + 2];
                bv = __builtin_bit_cast(bhalf8, (u32x4){u01.x, u01.y, u23.x, u23.y});
            } else {
#pragma unroll
                for (int e = 0; e < 8; ++e) bv[e] = 0;
            }
#pragma unroll
            for (int mt = 0; mt < 3; ++mt)
                acc2[mt][nt] = __builtin_amdgcn_mfma_f32_16x16x32_bf16(
                    w2A[mt], bv, acc2[mt][nt], 0, 0, 0);
        }
        // epilogue: h2 = tanh(y2) + h1[ch % 24]; write h2L row-major bf16x2
#pragma unroll
        for (int nt = 0; nt < 4; ++nt) {
            const int p = 64 * w + 16 * nt + m16;
#pragma unroll
            for (int mt = 0; mt < 3; ++mt) {
                const int cbase = 16 * mt + 4 * kg;          // 4 channels cbase..+3
                const int sbase = (cbase % 24) >> 1;         // even, no wrap
                const uint2 sk = *(const uint2*)&h1L[p * 14 + sbase];
                const float v0 = fast_tanh(acc2[mt][nt][0]) + bf16_lo(sk.x);
                const float v1 = fast_tanh(acc2[mt][nt][1]) + bf16_hi(sk.x);
                const float v2 = fast_tanh(acc2[mt][nt][2]) + bf16_lo(sk.y);
                const float v3 = fast_tanh(acc2[mt][nt][3]) + bf16_hi(sk.y);
                uint2 val;
                val.x = pk(v0, v1);
                val.y = pk(v2, v3);
                *(uint2*)&h2L[p * 26 + 8 * mt + 2 * kg] = val;
            }
        }
    }
    __syncthreads();   // B2a: h2L visible

    // ---- envA fragments: A[m][k], rows 0-3 = env_hi[d], rows 4-7 = env_lo[d] ----
    bhalf8 envA[2];
#pragma unroll
    for (int ks = 0; ks < 2; ++ks) {
        bhalf8 av;
#pragma unroll
        for (int e = 0; e < 8; ++e) {
            const int row = 64 * w + 32 * ks + 8 * kg + e;   // pair index (K dim)
            const float v = envs[row * 4 + (m16 & 3)];
            const unsigned short hb = bfb(v);
            const unsigned short lb = bfb(v - bff(hb));
            const unsigned short sel = (m16 < 4) ? hb : ((m16 < 8) ? lb : (unsigned short)0);
            av[e] = (short)sel;
        }
        envA[ks] = av;
    }

    // ---- h2A fragments for layer-3 A-operand: 4 Mtiles x 2 Kslices ----
    // K=48: ks=1 & kg>=2 -> zero registers (no LDS pad)
    bhalf8 h2A[4][2];
#pragma unroll
    for (int mt = 0; mt < 4; ++mt) {
        const int row = 64 * w + 16 * mt + m16;
        {
            const int wbase = row * 26 + 4 * kg;
            const uint2 u01 = *(const uint2*)&h2L[wbase];
            const uint2 u23 = *(const uint2*)&h2L[wbase + 2];
            h2A[mt][0] = __builtin_bit_cast(bhalf8, (u32x4){u01.x, u01.y, u23.x, u23.y});
        }
        if (kg < 2) {
            const int wbase = row * 26 + 16 + 4 * kg;
            const uint2 u01 = *(const uint2*)&h2L[wbase];
            const uint2 u23 = *(const uint2*)&h2L[wbase + 2];
            h2A[mt][1] = __builtin_bit_cast(bhalf8, (u32x4){u01.x, u01.y, u23.x, u23.y});
        } else {
            bhalf8 z;
#pragma unroll
            for (int e = 0; e < 8; ++e) z[e] = 0;
            h2A[mt][1] = z;
        }
    }

    // ---- Th2 = env^T h2 partial (resnet folded into T): 3 Ntiles of 16 ----
#pragma unroll
    for (int nt = 0; nt < 3; ++nt) {
        f32x4 acc = {0.f, 0.f, 0.f, 0.f};
#pragma unroll
        for (int ks = 0; ks < 2; ++ks) {
            bhalf8 bv;
#pragma unroll
            for (int e = 0; e < 8; ++e) {
                const int row = 64 * w + 32 * ks + 8 * kg + e;
                const int col = 16 * nt + m16;               // h2 channel
                const unsigned u = h2L[row * 26 + (col >> 1)];
                const unsigned short bits = (col & 1) ? (unsigned short)(u >> 16)
                                                      : (unsigned short)(u & 0xffffu);
                bv[e] = (short)bits;
            }
            acc = __builtin_amdgcn_mfma_f32_16x16x32_bf16(envA[ks], bv, acc, 0, 0, 0);
        }
#pragma unroll
        for (int rgi = 0; rgi < 4; ++rgi) {
            const float v = acc[rgi] + __shfl_down(acc[rgi], 16);  // hi + lo rows
            if (kg == 0) Th2L[(w * 4 + rgi) * 48 + 16 * nt + m16] = v;
        }
    }
    __syncthreads();   // B2b: envs/h1L/h2L reads done before GsT/TyL overlay writes

    // ---- layer 3 + Ty contraction, 3 N-slabs of 32 cols ----
#pragma unroll 1
    for (int sb = 0; sb < 3; ++sb) {
        const int nbase = 32 * sb;
        f32x4 acc[4][2];
#pragma unroll
        for (int nt = 0; nt < 2; ++nt) {
            const float b3v = b3[nbase + 16 * nt + m16];
#pragma unroll
            for (int mt = 0; mt < 4; ++mt)
                acc[mt][nt] = (f32x4){b3v, b3v, b3v, b3v};
        }
#pragma unroll
        for (int ks = 0; ks < 2; ++ks) {
#pragma unroll
            for (int nt = 0; nt < 2; ++nt) {
                // prepacked w3 fragment: [sb][ks][nt][lane][4]
                const bhalf8 wb = __builtin_bit_cast(bhalf8,
                    *(const u32x4*)&wsp[768 + ((((sb * 2 + ks) * 2 + nt) * 64 + l) * 4)]);
#pragma unroll
                for (int mt = 0; mt < 4; ++mt)
                    acc[mt][nt] = __builtin_amdgcn_mfma_f32_16x16x32_bf16(
                        h2A[mt][ks], wb, acc[mt][nt], 0, 0, 0);
            }
        }
        // epilogue: tanhY -> GsT col-major bf16 pairs
#pragma unroll
        for (int mt = 0; mt < 4; ++mt) {
#pragma unroll
            for (int nt = 0; nt < 2; ++nt) {
                const int col  = 16 * nt + m16;
                const int row0 = 64 * w + 16 * mt + 4 * kg;
                const float g0 = fast_tanh(acc[mt][nt][0]);
                const float g1 = fast_tanh(acc[mt][nt][1]);
                const float g2 = fast_tanh(acc[mt][nt][2]);
                const float g3 = fast_tanh(acc[mt][nt][3]);
                GsT[col * 66 + (row0 >> 1)]     = pk(g0, g1);
                GsT[col * 66 + (row0 >> 1) + 1] = pk(g2, g3);
            }
        }
        __syncthreads();   // B3: GsT writes ordered before reads
        // Ty partial for this slab's 32 cols
#pragma unroll
        for (int nt = 0; nt < 2; ++nt) {
            f32x4 ty = {0.f, 0.f, 0.f, 0.f};
#pragma unroll
            for (int ks = 0; ks < 2; ++ks) {
                const int col = 16 * nt + m16;
                const int wb2 = col * 66 + 32 * w + 16 * ks + 4 * kg;
                const uint2 u01 = *(const uint2*)&GsT[wb2];
                const uint2 u23 = *(const uint2*)&GsT[wb2 + 2];
                const bhalf8 bg = __builtin_bit_cast(bhalf8, (u32x4){u01.x, u01.y, u23.x, u23.y});
                ty = __builtin_amdgcn_mfma_f32_16x16x32_bf16(envA[ks], bg, ty, 0, 0, 0);
            }
#pragma unroll
            for (int rgi = 0; rgi < 4; ++rgi) {
                const float v = ty[rgi] + __shfl_down(ty[rgi], 16);
                if (kg == 0) TyL[(w * 4 + rgi) * 96 + nbase + 16 * nt + m16] = v;
            }
        }
        __syncthreads();   // B4: WAR before next slab's GsT overwrite / final combine
    }

    // ---- combine partials: Ts[d][n] = (Ty + tile(Th2)) / NNEI ----
#pragma unroll
    for (int j = 0; j < 3; ++j) {
        const int idx = t + 128 * j;         // 0..383
        const int d   = idx / 96;
        const int n   = idx - 96 * d;
        const int c   = (n >= 48) ? (n - 48) : n;
        const float v = TyL[(0 * 4 + d) * 96 + n] + TyL[(1 * 4 + d) * 96 + n]
                      + Th2L[(0 * 4 + d) * 48 + c] + Th2L[(1 * 4 + d) * 48 + c];
        Ts[d * 96 + n] = v * (1.0f / NNEI_);
    }
    __syncthreads();   // B5

    // ---- phase 4: D[m][k] = sum_d T[d][m]*T[d][k], k < 8 ----
    float* outp = out + (size_t)a * 768;
#pragma unroll
    for (int qq = 0; qq < 6; ++qq) {
        const int idx = t + 128 * qq;        // 0..767
        const int m = idx >> 3;
        const int k = idx & 7;
        const float d0 = Ts[0 * 96 + m] * Ts[0 * 96 + k];
        const float d1 = Ts[1 * 96 + m] * Ts[1 * 96 + k];
        const float d2 = Ts[2 * 96 + m] * Ts[2 * 96 + k];
        const float d3 = Ts[3 * 96 + m] * Ts[3 * 96 + k];
        outp[idx] = (d0 + d1) + (d2 + d3);
    }
}

extern "C" void kernel_launch(void* const* d_in, const int* in_sizes, int n_in,
                              void* d_out, int out_size, void* d_ws, size_t ws_size,
                              hipStream_t stream) {
    const float* coord = (const float*)d_in[0];
    const float* davg  = (const float*)d_in[1];
    const float* dstd  = (const float*)d_in[2];
    const float* w1    = (const float*)d_in[3];
    const float* b1    = (const float*)d_in[4];
    const float* w2    = (const float*)d_in[5];
    const float* b2    = (const float*)d_in[6];
    const float* w3    = (const float*)d_in[7];
    const float* b3    = (const float*)d_in[8];
    const int*   nlist = (const int*)d_in[9];
    float* outp = (float*)d_out;
    unsigned* wsp = (unsigned*)d_ws;

    prepack_weights<<<dim3(15), dim3(256), 0, stream>>>(w2, w3, wsp);
    descrpt_sea_kernel<<<dim3(NF_ * NLOC_), dim3(128), 0, stream>>>(
        coord, davg, dstd, w1, b1, w2, b2, w3, b3, nlist, wsp, outp);
}

// Round 10
// 219.513 us; speedup vs baseline: 1.5703x; 1.0922x over previous
//
#include <hip/hip_runtime.h>
#include <hip/hip_bf16.h>
#include <cstdint>

#define NF_   4
#define NLOC_ 4096
#define NALL_ 4096
#define NNEI_ 128
#define RCUT_ 6.0f
#define RMIN_ 0.5f

typedef __attribute__((ext_vector_type(8))) short    bhalf8;
typedef __attribute__((ext_vector_type(4))) float    f32x4;
typedef __attribute__((ext_vector_type(4))) unsigned u32x4;

// fast tanh via hardware exp + rcp: tanh(x) = 1 - 2/(exp(2x)+1); saturates correctly
__device__ __forceinline__ float fast_tanh(float x) {
    float e = __expf(2.0f * x);
    return 1.0f - 2.0f * __builtin_amdgcn_rcpf(e + 1.0f);
}
__device__ __forceinline__ unsigned short bfb(float v) {   // float -> bf16 bits (RNE)
    return __builtin_bit_cast(unsigned short, __float2bfloat16(v));
}
__device__ __forceinline__ float bff(unsigned short b) {
    return __builtin_bit_cast(float, (unsigned)b << 16);
}
__device__ __forceinline__ unsigned pk(float a, float b) { // pack 2 bf16
    return (unsigned)bfb(a) | ((unsigned)bfb(b) << 16);
}
__device__ __forceinline__ float bf16_lo(unsigned u) {
    return __builtin_bit_cast(float, u << 16);
}
__device__ __forceinline__ float bf16_hi(unsigned u) {
    return __builtin_bit_cast(float, u & 0xffff0000u);
}

// ---------------- weight-fragment prepack (runs every launch, trivial cost) ----
// d_ws layout (uints):
//   [0,768)     w2A frags:  [mt 3][lane 64][4]   (bf16x2; K=24 padded to 32 w/ 0)
//   [768,3840)  w3  frags:  [sb 3][ks 2][nt 2][lane 64][4]  (K=48 padded w/ 0)
__global__ void prepack_weights(const float* __restrict__ w2,
                                const float* __restrict__ w3,
                                unsigned* __restrict__ ws) {
    const int idx = threadIdx.x + blockIdx.x * 256;
    if (idx < 768) {
        const int u   = idx & 3;
        const int l   = (idx >> 2) & 63;
        const int mt  = idx >> 8;            // 0..2
        const int m16 = l & 15, kg = l >> 4;
        const int k0  = 8 * kg + 2 * u;
        const unsigned short s0 = (k0 < 24)     ? bfb(w2[k0 * 48 + 16 * mt + m16])       : (unsigned short)0;
        const unsigned short s1 = (k0 + 1 < 24) ? bfb(w2[(k0 + 1) * 48 + 16 * mt + m16]) : (unsigned short)0;
        ws[idx] = (unsigned)s0 | ((unsigned)s1 << 16);
    } else if (idx < 3840) {
        const int j   = idx - 768;
        const int u   = j & 3;
        const int l   = (j >> 2) & 63;
        const int nt  = (j >> 8) & 1;
        const int ks  = (j >> 9) & 1;
        const int sb  = j >> 10;             // 0..2
        const int m16 = l & 15, kg = l >> 4;
        const int k0  = 32 * ks + 8 * kg + 2 * u;
        const int col = 32 * sb + 16 * nt + m16;
        const unsigned short s0 = (k0 < 48)     ? bfb(w3[k0 * 96 + col])       : (unsigned short)0;
        const unsigned short s1 = (k0 + 1 < 48) ? bfb(w3[(k0 + 1) * 96 + col]) : (unsigned short)0;
        ws[idx] = (unsigned)s0 | ((unsigned)s1 << 16);
    }
}

// LDS map (uint words), total 3712 = 14848 B -> 11 blocks/CU LDS-wise
// (VGPR-capped to ~8 blocks via __launch_bounds__(128,4)):
//  timeline A (pre-B1b):  [0,512) envs fp32[128][4] ; [512,2304) h1L uint[128][14]
//  timeline B (post-B1b): [0,3328) h2L uint[128][26] (OVERLAYS envs+h1L — all
//                         envs/h1L consumers preloaded to regs before B1b)
//  timeline C (post-B2b): [0,2112) GsT uint[32][66]; [2112,2880) TyL f32[2][4][96];
//                         [2880,3264) Ts f32[4][96]   (all inside dead h2L)
//  always:                [3328,3712) Th2L f32[2][4][48]
__global__ __launch_bounds__(128, 4)
void descrpt_sea_kernel(
    const float* __restrict__ coord,
    const float* __restrict__ davg,
    const float* __restrict__ dstd,
    const float* __restrict__ w1, const float* __restrict__ b1,
    const float* __restrict__ w2, const float* __restrict__ b2,
    const float* __restrict__ w3, const float* __restrict__ b3,
    const int*   __restrict__ nlist,
    const unsigned* __restrict__ wsp,
    float* __restrict__ out)
{
    __shared__ __align__(16) unsigned smem[3712];
    float*    envs = (float*)smem;
    unsigned* h1L  = smem + 512;
    unsigned* h2L  = smem;                  // overlay of envs+h1L (timeline B)
    unsigned* GsT  = smem;                  // overlay of h2L (timeline C)
    float*    TyL  = (float*)(smem + 2112);
    float*    Ts   = (float*)(smem + 2880);
    float*    Th2L = (float*)(smem + 3328);

    const int t = threadIdx.x;              // 0..127: neighbor slot / pair row
    const int a = blockIdx.x;               // atom id (f*NLOC + i)
    const int f = a >> 12;
    const int i = a & 4095;

    // ---- phase 1: environment matrix row for this neighbor ----
    const float* cf = coord + (size_t)f * (NALL_ * 3);
    const float cix = cf[i * 3 + 0];
    const float ciy = cf[i * 3 + 1];
    const float ciz = cf[i * 3 + 2];
    const int nbr = nlist[(size_t)a * NNEI_ + t];
    float dx = cf[nbr * 3 + 0] - cix;
    float dy = cf[nbr * 3 + 1] - ciy;
    float dz = cf[nbr * 3 + 2] - ciz;
    float r2 = fmaf(dx, dx, fmaf(dy, dy, dz * dz)) + 1e-12f;
    float r  = __builtin_amdgcn_sqrtf(r2);
    float rinv = __builtin_amdgcn_rcpf(r);
    float uu = (r - RMIN_) * (1.0f / (RCUT_ - RMIN_));
    float u2 = uu * uu;
    float mid = (uu * u2) * fmaf(-6.0f, u2, fmaf(15.0f, uu, -10.0f)) + 1.0f;
    float sw  = (r < RMIN_) ? 1.0f : ((r < RCUT_) ? mid : 0.0f);
    float sv  = sw * rinv;
    float e0 = sv;
    float e1 = sv * dx * rinv;
    float e2 = sv * dy * rinv;
    float e3 = sv * dz * rinv;
    const float4 da  = reinterpret_cast<const float4*>(davg)[t];
    const float4 dsd = reinterpret_cast<const float4*>(dstd)[t];
    e0 = (e0 - da.x) * __builtin_amdgcn_rcpf(dsd.x);
    e1 = (e1 - da.y) * __builtin_amdgcn_rcpf(dsd.y);
    e2 = (e2 - da.z) * __builtin_amdgcn_rcpf(dsd.z);
    e3 = (e3 - da.w) * __builtin_amdgcn_rcpf(dsd.w);
    envs[t * 4 + 0] = e0;
    envs[t * 4 + 1] = e1;
    envs[t * 4 + 2] = e2;
    envs[t * 4 + 3] = e3;

    // ---- layer 1 per-lane (f32), h1 -> LDS bf16 row-major ----
    {
        const float x = e0;
        float h1[24];
#pragma unroll
        for (int j = 0; j < 24; ++j)
            h1[j] = fast_tanh(fmaf(x, w1[j], b1[j]));
#pragma unroll
        for (int j = 0; j < 12; ++j)
            h1L[t * 14 + j] = pk(h1[2 * j], h1[2 * j + 1]);
    }
    __syncthreads();   // B1: envs + h1L visible

    const int l   = t & 63;     // lane in wave
    const int w   = t >> 6;     // wave id (owns pair rows 64w..64w+63)
    const int m16 = l & 15;
    const int kg  = l >> 4;     // k-group 0..3

    // ---- PRELOADS (must ALL precede B1b: h2L overlays envs+h1L) ----
    // envA fragments: A[m][k], rows 0-3 = env_hi[d], rows 4-7 = env_lo[d]
    bhalf8 envA[2];
#pragma unroll
    for (int ks = 0; ks < 2; ++ks) {
        bhalf8 av;
#pragma unroll
        for (int e = 0; e < 8; ++e) {
            const int row = 64 * w + 32 * ks + 8 * kg + e;   // pair index (K dim)
            const float v = envs[row * 4 + (m16 & 3)];
            const unsigned short hb = bfb(v);
            const unsigned short lb = bfb(v - bff(hb));
            const unsigned short sel = (m16 < 4) ? hb : ((m16 < 8) ? lb : (unsigned short)0);
            av[e] = (short)sel;
        }
        envA[ks] = av;
    }
    // layer-2 B-frags (h1 col slices) + resnet-skip uint2s, from h1L
    bhalf8 bv[4];
    uint2  sk[4][3];
#pragma unroll
    for (int nt = 0; nt < 4; ++nt) {
        const int p = 64 * w + 16 * nt + m16;
        if (kg < 3) {
            const uint2 u01 = *(const uint2*)&h1L[p * 14 + 4 * kg];
            const uint2 u23 = *(const uint2*)&h1L[p * 14 + 4 * kg + 2];
            bv[nt] = __builtin_bit_cast(bhalf8, (u32x4){u01.x, u01.y, u23.x, u23.y});
        } else {
            bhalf8 z;
#pragma unroll
            for (int e = 0; e < 8; ++e) z[e] = 0;
            bv[nt] = z;
        }
        // skip bases per mt (cbase=16mt+4kg; sbase=(cbase%24)>>1):
        sk[nt][0] = *(const uint2*)&h1L[p * 14 + 2 * kg];
        sk[nt][1] = *(const uint2*)&h1L[p * 14 + ((kg < 2) ? (8 + 2 * kg) : (2 * kg - 4))];
        sk[nt][2] = *(const uint2*)&h1L[p * 14 + 4 + 2 * kg];
    }
    __syncthreads();   // B1b: all envs/h1L reads done -> h2L overlay writes legal

    // ---- layer 2 via MFMA, TRANSPOSED: Y2^T = w2^T . h1^T ----
    // C tile: col = pair (m16), rows = channels 16mt+4kg+reg -> epilogue writes
    // row-major h2L directly. A-frags prepacked in ws (K=24 padded to 32).
    {
        bhalf8 w2A[3];
#pragma unroll
        for (int mt = 0; mt < 3; ++mt)
            w2A[mt] = __builtin_bit_cast(bhalf8, *(const u32x4*)&wsp[(mt * 64 + l) * 4]);

        f32x4 acc2[3][4];
#pragma unroll
        for (int mt = 0; mt < 3; ++mt) {
            const float4 bi = *(const float4*)&b2[16 * mt + 4 * kg];
#pragma unroll
            for (int nt = 0; nt < 4; ++nt)
                acc2[mt][nt] = (f32x4){bi.x, bi.y, bi.z, bi.w};
        }
#pragma unroll
        for (int nt = 0; nt < 4; ++nt) {
#pragma unroll
            for (int mt = 0; mt < 3; ++mt)
                acc2[mt][nt] = __builtin_amdgcn_mfma_f32_16x16x32_bf16(
                    w2A[mt], bv[nt], acc2[mt][nt], 0, 0, 0);
        }
        // epilogue: h2 = tanh(y2) + h1[ch % 24]; write h2L row-major bf16x2
#pragma unroll
        for (int nt = 0; nt < 4; ++nt) {
            const int p = 64 * w + 16 * nt + m16;
#pragma unroll
            for (int mt = 0; mt < 3; ++mt) {
                const float v0 = fast_tanh(acc2[mt][nt][0]) + bf16_lo(sk[nt][mt].x);
                const float v1 = fast_tanh(acc2[mt][nt][1]) + bf16_hi(sk[nt][mt].x);
                const float v2 = fast_tanh(acc2[mt][nt][2]) + bf16_lo(sk[nt][mt].y);
                const float v3 = fast_tanh(acc2[mt][nt][3]) + bf16_hi(sk[nt][mt].y);
                uint2 val;
                val.x = pk(v0, v1);
                val.y = pk(v2, v3);
                *(uint2*)&h2L[p * 26 + 8 * mt + 2 * kg] = val;
            }
        }
    }
    __syncthreads();   // B2a: h2L visible

    // ---- h2A fragments for layer-3 A-operand: 4 Mtiles x 2 Kslices ----
    // K=48: ks=1 & kg>=2 -> zero registers (no LDS pad)
    bhalf8 h2A[4][2];
#pragma unroll
    for (int mt = 0; mt < 4; ++mt) {
        const int row = 64 * w + 16 * mt + m16;
        {
            const int wbase = row * 26 + 4 * kg;
            const uint2 u01 = *(const uint2*)&h2L[wbase];
            const uint2 u23 = *(const uint2*)&h2L[wbase + 2];
            h2A[mt][0] = __builtin_bit_cast(bhalf8, (u32x4){u01.x, u01.y, u23.x, u23.y});
        }
        if (kg < 2) {
            const int wbase = row * 26 + 16 + 4 * kg;
            const uint2 u01 = *(const uint2*)&h2L[wbase];
            const uint2 u23 = *(const uint2*)&h2L[wbase + 2];
            h2A[mt][1] = __builtin_bit_cast(bhalf8, (u32x4){u01.x, u01.y, u23.x, u23.y});
        } else {
            bhalf8 z;
#pragma unroll
            for (int e = 0; e < 8; ++e) z[e] = 0;
            h2A[mt][1] = z;
        }
    }

    // ---- Th2 = env^T h2 partial (resnet folded into T): 3 Ntiles of 16 ----
#pragma unroll
    for (int nt = 0; nt < 3; ++nt) {
        f32x4 acc = {0.f, 0.f, 0.f, 0.f};
#pragma unroll
        for (int ks = 0; ks < 2; ++ks) {
            bhalf8 bvv;
#pragma unroll
            for (int e = 0; e < 8; ++e) {
                const int row = 64 * w + 32 * ks + 8 * kg + e;
                const int col = 16 * nt + m16;               // h2 channel
                const unsigned u = h2L[row * 26 + (col >> 1)];
                const unsigned short bits = (col & 1) ? (unsigned short)(u >> 16)
                                                      : (unsigned short)(u & 0xffffu);
                bvv[e] = (short)bits;
            }
            acc = __builtin_amdgcn_mfma_f32_16x16x32_bf16(envA[ks], bvv, acc, 0, 0, 0);
        }
#pragma unroll
        for (int rgi = 0; rgi < 4; ++rgi) {
            const float v = acc[rgi] + __shfl_down(acc[rgi], 16);  // hi + lo rows
            if (kg == 0) Th2L[(w * 4 + rgi) * 48 + 16 * nt + m16] = v;
        }
    }
    __syncthreads();   // B2b: h2L reads done before GsT/TyL/Ts overlay writes

    // ---- layer 3 + Ty contraction, 3 N-slabs of 32 cols ----
#pragma unroll 1
    for (int sb = 0; sb < 3; ++sb) {
        const int nbase = 32 * sb;
        f32x4 acc[4][2];
#pragma unroll
        for (int nt = 0; nt < 2; ++nt) {
            const float b3v = b3[nbase + 16 * nt + m16];
#pragma unroll
            for (int mt = 0; mt < 4; ++mt)
                acc[mt][nt] = (f32x4){b3v, b3v, b3v, b3v};
        }
#pragma unroll
        for (int ks = 0; ks < 2; ++ks) {
#pragma unroll
            for (int nt = 0; nt < 2; ++nt) {
                // prepacked w3 fragment: [sb][ks][nt][lane][4]
                const bhalf8 wb = __builtin_bit_cast(bhalf8,
                    *(const u32x4*)&wsp[768 + ((((sb * 2 + ks) * 2 + nt) * 64 + l) * 4)]);
#pragma unroll
                for (int mt = 0; mt < 4; ++mt)
                    acc[mt][nt] = __builtin_amdgcn_mfma_f32_16x16x32_bf16(
                        h2A[mt][ks], wb, acc[mt][nt], 0, 0, 0);
            }
        }
        // epilogue: tanhY -> GsT col-major bf16 pairs
#pragma unroll
        for (int mt = 0; mt < 4; ++mt) {
#pragma unroll
            for (int nt = 0; nt < 2; ++nt) {
                const int col  = 16 * nt + m16;
                const int row0 = 64 * w + 16 * mt + 4 * kg;
                const float g0 = fast_tanh(acc[mt][nt][0]);
                const float g1 = fast_tanh(acc[mt][nt][1]);
                const float g2 = fast_tanh(acc[mt][nt][2]);
                const float g3 = fast_tanh(acc[mt][nt][3]);
                GsT[col * 66 + (row0 >> 1)]     = pk(g0, g1);
                GsT[col * 66 + (row0 >> 1) + 1] = pk(g2, g3);
            }
        }
        __syncthreads();   // B3: GsT writes ordered before reads
        // Ty partial for this slab's 32 cols
#pragma unroll
        for (int nt = 0; nt < 2; ++nt) {
            f32x4 ty = {0.f, 0.f, 0.f, 0.f};
#pragma unroll
            for (int ks = 0; ks < 2; ++ks) {
                const int col = 16 * nt + m16;
                const int wb2 = col * 66 + 32 * w + 16 * ks + 4 * kg;
                const uint2 u01 = *(const uint2*)&GsT[wb2];
                const uint2 u23 = *(const uint2*)&GsT[wb2 + 2];
                const bhalf8 bg = __builtin_bit_cast(bhalf8, (u32x4){u01.x, u01.y, u23.x, u23.y});
                ty = __builtin_amdgcn_mfma_f32_16x16x32_bf16(envA[ks], bg, ty, 0, 0, 0);
            }
#pragma unroll
            for (int rgi = 0; rgi < 4; ++rgi) {
                const float v = ty[rgi] + __shfl_down(ty[rgi], 16);
                if (kg == 0) TyL[(w * 4 + rgi) * 96 + nbase + 16 * nt + m16] = v;
            }
        }
        __syncthreads();   // B4: WAR before next slab's GsT overwrite / final combine
    }

    // ---- combine partials: Ts[d][n] = (Ty + tile(Th2)) / NNEI ----
#pragma unroll
    for (int j = 0; j < 3; ++j) {
        const int idx = t + 128 * j;         // 0..383
        const int d   = idx / 96;
        const int n   = idx - 96 * d;
        const int c   = (n >= 48) ? (n - 48) : n;
        const float v = TyL[(0 * 4 + d) * 96 + n] + TyL[(1 * 4 + d) * 96 + n]
                      + Th2L[(0 * 4 + d) * 48 + c] + Th2L[(1 * 4 + d) * 48 + c];
        Ts[d * 96 + n] = v * (1.0f / NNEI_);
    }
    __syncthreads();   // B5

    // ---- phase 4: D[m][k] = sum_d T[d][m]*T[d][k], k < 8 ----
    float* outp = out + (size_t)a * 768;
#pragma unroll
    for (int qq = 0; qq < 6; ++qq) {
        const int idx = t + 128 * qq;        // 0..767
        const int m = idx >> 3;
        const int k = idx & 7;
        const float d0 = Ts[0 * 96 + m] * Ts[0 * 96 + k];
        const float d1 = Ts[1 * 96 + m] * Ts[1 * 96 + k];
        const float d2 = Ts[2 * 96 + m] * Ts[2 * 96 + k];
        const float d3 = Ts[3 * 96 + m] * Ts[3 * 96 + k];
        outp[idx] = (d0 + d1) + (d2 + d3);
    }
}

extern "C" void kernel_launch(void* const* d_in, const int* in_sizes, int n_in,
                              void* d_out, int out_size, void* d_ws, size_t ws_size,
                              hipStream_t stream) {
    const float* coord = (const float*)d_in[0];
    const float* davg  = (const float*)d_in[1];
    const float* dstd  = (const float*)d_in[2];
    const float* w1    = (const float*)d_in[3];
    const float* b1    = (const float*)d_in[4];
    const float* w2    = (const float*)d_in[5];
    const float* b2    = (const float*)d_in[6];
    const float* w3    = (const float*)d_in[7];
    const float* b3    = (const float*)d_in[8];
    const int*   nlist = (const int*)d_in[9];
    float* outp = (float*)d_out;
    unsigned* wsp = (unsigned*)d_ws;

    prepack_weights<<<dim3(15), dim3(256), 0, stream>>>(w2, w3, wsp);
    descrpt_sea_kernel<<<dim3(NF_ * NLOC_), dim3(128), 0, stream>>>(
        coord, davg, dstd, w1, b1, w2, b2, w3, b3, nlist, wsp, outp);
}